// Round 2
// baseline (204.379 us; speedup 1.0000x reference)
//
#include <hip/hip_runtime.h>
#include <stdint.h>

typedef __attribute__((ext_vector_type(8)))  short  short8;
typedef __attribute__((ext_vector_type(8)))  __bf16 bf16x8;
typedef __attribute__((ext_vector_type(16))) float  floatx16;
typedef __attribute__((ext_vector_type(4)))  float  floatx4;
typedef __attribute__((ext_vector_type(2)))  float  float2v;
typedef __attribute__((ext_vector_type(4)))  uint32_t uint4v;

union Frag { short8 s; bf16x8 v; uint4v d; };
union FU   { float f; uint32_t u; };

// round-to-nearest-even f32 -> bf16 (setup only)
__device__ __forceinline__ short f2bf(float f) {
    FU x; x.f = f;
    uint32_t r = x.u + 0x7fffu + ((x.u >> 16) & 1u);
    return (short)(r >> 16);
}

// pack two f32 -> bf16x2 dword, round-half-up: 2 adds + 1 v_perm
__device__ __forceinline__ uint32_t pack_bf2(float lo, float hi) {
    FU a, b; a.f = lo; b.f = hi;
    return __builtin_amdgcn_perm(b.u + 0x8000u, a.u + 0x8000u, 0x07060302u);
}

__device__ __forceinline__ float fexp2(float x) { return __builtin_amdgcn_exp2f(x); }
__device__ __forceinline__ float frcp(float x)  { return __builtin_amdgcn_rcpf(x); }

// T = exp2(min(arg,15)) + 1 for the pair (acc[j], acc[j+8]).
// No lower clamp needed: exp2 underflow -> 0 -> T=1 is the exact limit.
// Upper clamp 15 keeps the 8-way product <= 2^121 (no overflow);
// tanh error at the clamp ~6e-5, far under tolerance.
__device__ __forceinline__ float2v tpair(float a, float b) {
    float2v t;
    t.x = fexp2(fminf(a, 15.0f));
    t.y = fexp2(fminf(b, 15.0f));
    return t + 1.0f;
}

// y[b] = a0 + sum_k bk[k] * tanh(ck[k,:].z[b,:] + dk[k])
//
// D = mfma_32x32x16_bf16(A=s*ck, B=z, C=s*dk) -> D[node][row] = s*(dot+dk),
// s = 2*log2(e); col(lane&31)=batch row, node=(reg&3)+8*(reg>>2)+4*(lane>>5).
// tanh(t) = 1 - 2/(exp2(s*t)+1); 8-way shared denominator per half:
//   sum bj/Tj = [ (n01*P23+n23*P01)*P45P67 + (n45*P67+n67*P45)*P01P23 ] * rcp(P)
//   with nXY = bX*TY + bY*TX, P = prod(T0..T7)  -> 2 rcp per 16 values.
//
// R11 (from R9/R10: VALUBusy=32%, MfmaUtil=2%, Occ=19%, 4 waves/SIMD,
// everything idle -> residency/latency-bound; R10's LDS tables likely got
// CSE'd back into VGPRs -> no occupancy gain):
//  - __launch_bounds__(256,7): force VGPR<=72 -> 7 waves/SIMD resident.
//  - 4 tiles/wave, depth-2 z pipeline: 2x wave count, finer TLP, zb=16 regs.
//  - Per-tile laundered index (asm) on the LDS table pointers: defeats CSE,
//    guarantees per-tile ds_read_b128 broadcasts (2-way aliasing = free)
//    instead of 48 resident VGPRs of constants.
//  - z + ck loads issue BEFORE the table-build barrier: the forced
//    vmcnt(0) drain at s_barrier overlaps dk/bk fetch latency.
__global__ __launch_bounds__(256, 7) void mave_kernel(
    const float* __restrict__ z,
    const float* __restrict__ a0,
    const float* __restrict__ bk,
    const float* __restrict__ ck,
    const float* __restrict__ dk,
    float* __restrict__ out,
    int ntiles)
{
    const int lane = threadIdx.x & 63;
    const int m    = lane & 31;
    const int g    = lane >> 5;
    const float S  = 2.885390081777927f;  // 2*log2(e)

    __shared__ __align__(16) float   cinitL[2][2][16];  // [g][h][reg]
    __shared__ __align__(16) float2v nbL[2][2][8];      // [g][h][j] = (-2bk pair)
    __shared__ float baseL;

    const int wid   = (int)((blockIdx.x * blockDim.x + threadIdx.x) >> 6);
    const int tile0 = wid * 4;
    const int tlast = ntiles - 1;

    const float* zp = z + (size_t)m * 16 + g * 8;

    // ---- issue depth-2 z loads FIRST (latency overlaps table build) ----
    floatx4 zb[2][2];
    #pragma unroll
    for (int i = 0; i < 2; ++i) {
        int ti = tile0 + i; if (ti > tlast) ti = tlast;   // clamp: benign dup
        const float* q = zp + (size_t)ti * 512;
        zb[i][0] = *(const floatx4*)q;
        zb[i][1] = *(const floatx4*)(q + 4);
    }

    // ---- A-fragments (ck loads also in flight across the barrier) ----
    Frag af[2];
    {
        const float* c0 = ck + m * 16 + g * 8;
        #pragma unroll
        for (int e = 0; e < 8; ++e) {
            af[0].s[e] = f2bf(c0[e] * S);          // nodes 0..31 rows
            af[1].s[e] = f2bf(c0[512 + e] * S);    // nodes 32..63 rows
        }
    }

    // ---- per-block constant tables (wave 0 only) ----
    if (threadIdx.x < 64) {
        const int t = threadIdx.x;
        {   // 64 entries: (g,h,reg) in MFMA C/D order
            const int gg = t >> 5, hh = (t >> 4) & 1, r = t & 15;
            const int n  = (r & 3) + 8 * (r >> 2) + 4 * gg + 32 * hh;
            cinitL[gg][hh][r] = S * dk[n];
        }
        if (t < 32) {  // 32 entries: pair j = (node(j), node(j)+16)
            const int gg = t >> 4, hh = (t >> 3) & 1, j = t & 7;
            const int nl = (j & 3) + 8 * (j >> 2) + 4 * gg + 32 * hh;
            float2v nb; nb.x = -2.0f * bk[nl]; nb.y = -2.0f * bk[nl + 16];
            nbL[gg][hh][j] = nb;
        }
        float bv = bk[t];
        #pragma unroll
        for (int d = 1; d < 64; d <<= 1) bv += __shfl_xor(bv, d, 64);
        if (t == 0) baseL = a0[0] + bv;
    }
    __syncthreads();

    if (tile0 >= ntiles) return;   // after barrier: all waves participated

    const floatx4* cqg = (const floatx4*)&cinitL[g][0][0];  // 8 quads (h*4+q)
    const floatx4* nqg = (const floatx4*)&nbL[g][0][0];     // 8 quads (h*4+k)

    // ---- 4 tiles, straight-line, rolling refill at distance 2 ----
    float yv[4];
    #pragma unroll
    for (int i = 0; i < 4; ++i) {
        Frag bfr;
        bfr.d[0] = pack_bf2(zb[i & 1][0].x, zb[i & 1][0].y);
        bfr.d[1] = pack_bf2(zb[i & 1][0].z, zb[i & 1][0].w);
        bfr.d[2] = pack_bf2(zb[i & 1][1].x, zb[i & 1][1].y);
        bfr.d[3] = pack_bf2(zb[i & 1][1].z, zb[i & 1][1].w);

        if (i + 2 < 4) {                  // compile-time guard (unrolled)
            int ti = tile0 + i + 2; if (ti > tlast) ti = tlast;
            const float* q = zp + (size_t)ti * 512;
            zb[i & 1][0] = *(const floatx4*)q;
            zb[i & 1][1] = *(const floatx4*)(q + 4);
        }

        // laundered per-tile index: forces fresh LDS broadcast reads
        // (no CSE across tiles -> constants never become resident VGPRs)
        int zz = 0;
        asm volatile("" : "+v"(zz));
        const floatx4* cq = cqg + zz;
        const floatx4* nq = nqg + zz;

        float ya = 0.0f;
        #pragma unroll
        for (int h = 0; h < 2; ++h) {
            union { floatx16 v; floatx4 q[4]; } C;
            C.q[0] = cq[h * 4 + 0]; C.q[1] = cq[h * 4 + 1];
            C.q[2] = cq[h * 4 + 2]; C.q[3] = cq[h * 4 + 3];
            floatx16 acc = __builtin_amdgcn_mfma_f32_32x32x16_bf16(
                af[h].v, bfr.v, C.v, 0, 0, 0);

            union { floatx4 q; float2v p[2]; } N0, N1, N2, N3;
            N0.q = nq[h * 4 + 0];   // nb[j=0], nb[j=1]
            N1.q = nq[h * 4 + 1];   // nb[j=2], nb[j=3]
            N2.q = nq[h * 4 + 2];   // nb[j=4], nb[j=5]
            N3.q = nq[h * 4 + 3];   // nb[j=6], nb[j=7]

            // grouped so T pairs die early (keeps transient peak low)
            float2v T0 = tpair(acc[0], acc[8]);
            float2v T1 = tpair(acc[1], acc[9]);
            float2v P01 = T0 * T1;
            float2v n01 = N0.p[0] * T1 + N0.p[1] * T0;
            float2v T2 = tpair(acc[2], acc[10]);
            float2v T3 = tpair(acc[3], acc[11]);
            float2v P23 = T2 * T3;
            float2v n23 = N1.p[0] * T3 + N1.p[1] * T2;
            float2v T4 = tpair(acc[4], acc[12]);
            float2v T5 = tpair(acc[5], acc[13]);
            float2v P45 = T4 * T5;
            float2v n45 = N2.p[0] * T5 + N2.p[1] * T4;
            float2v T6 = tpair(acc[6], acc[14]);
            float2v T7 = tpair(acc[7], acc[15]);
            float2v P67 = T6 * T7;
            float2v n67 = N3.p[0] * T7 + N3.p[1] * T6;

            float2v PA = P01 * P23, PB = P45 * P67;
            float2v nA = n01 * P23 + n23 * P01;
            float2v nB = n45 * P67 + n67 * P45;
            float2v P  = PA * PB;
            float2v Num = nA * PB + nB * PA;
            float2v R; R.x = frcp(P.x); R.y = frcp(P.y);
            float2v Yh = Num * R;
            ya += Yh.x + Yh.y;
        }
        yv[i] = ya;
    }

    // ---- batched cross-half merge (one lgkm drain) + stores ----
    const float base = baseL;
    float ov[4];
    #pragma unroll
    for (int i = 0; i < 4; ++i) ov[i] = __shfl_xor(yv[i], 32, 64);
    if (g == 0) {
        #pragma unroll
        for (int i = 0; i < 4; ++i) {
            int ti = tile0 + i; if (ti > tlast) ti = tlast;
            out[(size_t)ti * 32 + m] = base + yv[i] + ov[i];
        }
    }
}

extern "C" void kernel_launch(void* const* d_in, const int* in_sizes, int n_in,
                              void* d_out, int out_size, void* d_ws, size_t ws_size,
                              hipStream_t stream) {
    const float* z  = (const float*)d_in[0];
    const float* a0 = (const float*)d_in[1];
    const float* bk = (const float*)d_in[2];
    const float* ck = (const float*)d_in[3];
    const float* dk = (const float*)d_in[4];
    float* out = (float*)d_out;

    const int B      = in_sizes[0] / 16;       // z is [B,16]
    const int ntiles = B / 32;                 // 32 batch rows per wave-tile

    // 4 tiles/wave, 4 waves/block -> 16 tiles/block; 4096 blocks at B=2M
    const int blocks = (ntiles + 15) / 16;
    hipLaunchKernelGGL(mave_kernel, dim3(blocks), dim3(256), 0, stream,
                       z, a0, bk, ck, dk, out, ntiles);
}

// Round 3
// 196.492 us; speedup vs baseline: 1.0401x; 1.0401x over previous
//
#include <hip/hip_runtime.h>
#include <stdint.h>

typedef __attribute__((ext_vector_type(8)))  short  short8;
typedef __attribute__((ext_vector_type(8)))  __bf16 bf16x8;
typedef __attribute__((ext_vector_type(16))) float  floatx16;
typedef __attribute__((ext_vector_type(4)))  float  floatx4;
typedef __attribute__((ext_vector_type(2)))  float  float2v;
typedef __attribute__((ext_vector_type(4)))  uint32_t uint4v;

union Frag { short8 s; bf16x8 v; uint4v d; };
union FU   { float f; uint32_t u; };

// round-to-nearest-even f32 -> bf16 (setup only)
__device__ __forceinline__ short f2bf(float f) {
    FU x; x.f = f;
    uint32_t r = x.u + 0x7fffu + ((x.u >> 16) & 1u);
    return (short)(r >> 16);
}

// pack two f32 -> bf16x2 dword, round-half-up: 2 adds + 1 v_perm
__device__ __forceinline__ uint32_t pack_bf2(float lo, float hi) {
    FU a, b; a.f = lo; b.f = hi;
    return __builtin_amdgcn_perm(b.u + 0x8000u, a.u + 0x8000u, 0x07060302u);
}

__device__ __forceinline__ float fexp2(float x) { return __builtin_amdgcn_exp2f(x); }
__device__ __forceinline__ float frcp(float x)  { return __builtin_amdgcn_rcpf(x); }

// T = exp2(min(arg,15)) + 1 for the pair (acc[j], acc[j+8]).
// No lower clamp: exp2 underflow -> 0 -> T=1 is the exact limit.
// Upper clamp 15 keeps the 8-way product <= 2^121 (no overflow);
// tanh error at the clamp ~6e-5, far under tolerance.
__device__ __forceinline__ float2v tpair(float a, float b) {
    float2v t;
    t.x = fexp2(fminf(a, 15.0f));
    t.y = fexp2(fminf(b, 15.0f));
    return t + 1.0f;
}

// y[b] = a0 + sum_k bk[k] * tanh(ck[k,:].z[b,:] + dk[k])
//
// D = mfma_32x32x16_bf16(A=s*ck, B=z, C=s*dk) -> D[node][row] = s*(dot+dk),
// s = 2*log2(e); col(lane&31)=batch row, node=(reg&3)+8*(reg>>2)+4*(lane>>5).
// tanh(t) = 1 - 2/(exp2(s*t)+1); 8-way shared denominator per half:
//   sum bj/Tj = [ (n01*P23+n23*P01)*P45P67 + (n45*P67+n67*P45)*P01P23 ] * rcp(P)
//
// R12 theory (cold-regime concurrency): the harness's 536MB fill evicts z
// from L3 every iteration, so measured dispatches re-read 128MB from HBM,
// yet achieve only ~1.6 TB/s (fill kernel proves 6.9 TB/s). Cause: too few
// bytes in flight. Old designs leaked concurrency two ways: (a) the
// __syncthreads after z-load issue forces a vmcnt(0)+lgkmcnt(0) drain and
// couples 4 waves to the slowest cold load; (b) preamble consumed loads
// issued AFTER z -> in-order vmcnt drained z early. Fix:
//  - 2 tiles/wave, all 4 z dwordx4 issued upfront (4KB/wave in flight).
//  - NO barrier: each wave builds its own 512B LDS table copy.
//  - Load order ck -> dk/bk/a0 -> z (z youngest: preamble waits never
//    touch it); compiler emits exact counted vmcnt(2)/vmcnt(0) at tiles.
//  - __launch_bounds__(256,7): small body (zb=16, h-split acc=16, no
//    resident tables) -> ~70 VGPR -> 7 waves/SIMD, 28 waves/CU.
// In-flight ~= 28 waves x 4KB = 112KB/CU ~= 28MB device >> 6MB needed.
__global__ __launch_bounds__(256, 7) void mave_kernel(
    const float* __restrict__ z,
    const float* __restrict__ a0,
    const float* __restrict__ bk,
    const float* __restrict__ ck,
    const float* __restrict__ dk,
    float* __restrict__ out,
    int ntiles)
{
    const int lane = threadIdx.x & 63;
    const int m    = lane & 31;
    const int g    = lane >> 5;
    const int widx = threadIdx.x >> 6;
    const float S  = 2.885390081777927f;  // 2*log2(e)

    // per-WAVE table copies: no cross-wave sharing -> no __syncthreads
    __shared__ __align__(16) float   cinitL[4][2][2][16];  // [wave][g][h][reg]
    __shared__ __align__(16) float2v nbL[4][2][2][8];      // [wave][g][h][j]

    const int wid   = (int)((blockIdx.x * blockDim.x + threadIdx.x) >> 6);
    const int tile0 = wid * 2;
    if (tile0 >= ntiles) return;
    const int tlast = ntiles - 1;

    // ---- loads, oldest first: ck (A fragments) ----
    const float* c0 = ck + m * 16 + g * 8;
    floatx4 ckv0 = *(const floatx4*)c0;
    floatx4 ckv1 = *(const floatx4*)(c0 + 4);
    floatx4 ckv2 = *(const floatx4*)(c0 + 512);
    floatx4 ckv3 = *(const floatx4*)(c0 + 516);

    // ---- table sources (per-lane gathers; small, L1/L2-hot) ----
    const int tl = lane;
    const int gg = tl >> 5, hh = (tl >> 4) & 1, rr = tl & 15;
    const int nc = (rr & 3) + 8 * (rr >> 2) + 4 * gg + 32 * hh;
    float dkv = dk[nc];
    float bkt = bk[tl];
    const int g2 = tl >> 4, h2 = (tl >> 3) & 1, j2 = tl & 7;
    const int nl = (j2 & 3) + 8 * (j2 >> 2) + 4 * g2 + 32 * h2;
    float bnl = 0.0f, bnh = 0.0f;
    if (tl < 32) { bnl = bk[nl]; bnh = bk[nl + 16]; }   // exec-masked (nl OOB for tl>=32)
    float a0v = a0[0];

    // ---- z loads LAST (youngest): preamble waits never drain them ----
    const float* zp = z + (size_t)m * 16 + g * 8;
    floatx4 zb[2][2];
    #pragma unroll
    for (int i = 0; i < 2; ++i) {
        int ti = tile0 + i; if (ti > tlast) ti = tlast;   // clamp: benign dup
        const float* q = zp + (size_t)ti * 512;
        zb[i][0] = *(const floatx4*)q;
        zb[i][1] = *(const floatx4*)(q + 4);
    }

    // ---- consume ck (vmcnt wait covers only ck; z stays in flight) ----
    Frag af[2];
    #pragma unroll
    for (int e = 0; e < 4; ++e) {
        af[0].s[e]     = f2bf(ckv0[e] * S);
        af[0].s[e + 4] = f2bf(ckv1[e] * S);
        af[1].s[e]     = f2bf(ckv2[e] * S);
        af[1].s[e + 4] = f2bf(ckv3[e] * S);
    }

    // ---- per-wave tables; same-wave RAW ordered by lgkmcnt only ----
    cinitL[widx][gg][hh][rr] = S * dkv;
    if (tl < 32) {
        float2v nb; nb.x = -2.0f * bnl; nb.y = -2.0f * bnh;
        nbL[widx][g2][h2][j2] = nb;
    }
    float bv = bkt;
    #pragma unroll
    for (int d = 1; d < 64; d <<= 1) bv += __shfl_xor(bv, d, 64);
    const float base = a0v + bv;   // all lanes hold it

    const floatx4* cqg = (const floatx4*)&cinitL[widx][g][0][0];  // 8 quads
    const floatx4* nqg = (const floatx4*)&nbL[widx][g][0][0];     // 8 quads

    // ---- 2 tiles, straight-line ----
    float yv[2];
    #pragma unroll
    for (int i = 0; i < 2; ++i) {
        Frag bfr;
        bfr.d[0] = pack_bf2(zb[i][0].x, zb[i][0].y);
        bfr.d[1] = pack_bf2(zb[i][0].z, zb[i][0].w);
        bfr.d[2] = pack_bf2(zb[i][1].x, zb[i][1].y);
        bfr.d[3] = pack_bf2(zb[i][1].z, zb[i][1].w);

        // laundered per-tile index: forces fresh LDS broadcast reads
        // (keeps the constant tables OUT of resident VGPRs)
        int zz = 0;
        asm volatile("" : "+v"(zz));
        const floatx4* cq = cqg + zz;
        const floatx4* nq = nqg + zz;

        float ya = 0.0f;
        #pragma unroll
        for (int h = 0; h < 2; ++h) {
            union { floatx16 v; floatx4 q[4]; } C;
            C.q[0] = cq[h * 4 + 0]; C.q[1] = cq[h * 4 + 1];
            C.q[2] = cq[h * 4 + 2]; C.q[3] = cq[h * 4 + 3];
            floatx16 acc = __builtin_amdgcn_mfma_f32_32x32x16_bf16(
                af[h].v, bfr.v, C.v, 0, 0, 0);

            union { floatx4 q; float2v p[2]; } N0, N1, N2, N3;
            N0.q = nq[h * 4 + 0];   // nb[j=0], nb[j=1]
            N1.q = nq[h * 4 + 1];   // nb[j=2], nb[j=3]
            N2.q = nq[h * 4 + 2];   // nb[j=4], nb[j=5]
            N3.q = nq[h * 4 + 3];   // nb[j=6], nb[j=7]

            float2v T0 = tpair(acc[0], acc[8]);
            float2v T1 = tpair(acc[1], acc[9]);
            float2v P01 = T0 * T1;
            float2v n01 = N0.p[0] * T1 + N0.p[1] * T0;
            float2v T2 = tpair(acc[2], acc[10]);
            float2v T3 = tpair(acc[3], acc[11]);
            float2v P23 = T2 * T3;
            float2v n23 = N1.p[0] * T3 + N1.p[1] * T2;
            float2v T4 = tpair(acc[4], acc[12]);
            float2v T5 = tpair(acc[5], acc[13]);
            float2v P45 = T4 * T5;
            float2v n45 = N2.p[0] * T5 + N2.p[1] * T4;
            float2v T6 = tpair(acc[6], acc[14]);
            float2v T7 = tpair(acc[7], acc[15]);
            float2v P67 = T6 * T7;
            float2v n67 = N3.p[0] * T7 + N3.p[1] * T6;

            float2v PA = P01 * P23, PB = P45 * P67;
            float2v nA = n01 * P23 + n23 * P01;
            float2v nB = n45 * P67 + n67 * P45;
            float2v P  = PA * PB;
            float2v Num = nA * PB + nB * PA;
            float2v R; R.x = frcp(P.x); R.y = frcp(P.y);
            float2v Yh = Num * R;
            ya += Yh.x + Yh.y;
        }
        yv[i] = ya;
    }

    // ---- cross-half merge + stores ----
    float ov[2];
    #pragma unroll
    for (int i = 0; i < 2; ++i) ov[i] = __shfl_xor(yv[i], 32, 64);
    if (g == 0) {
        #pragma unroll
        for (int i = 0; i < 2; ++i) {
            int ti = tile0 + i; if (ti > tlast) ti = tlast;
            out[(size_t)ti * 32 + m] = base + yv[i] + ov[i];
        }
    }
}

extern "C" void kernel_launch(void* const* d_in, const int* in_sizes, int n_in,
                              void* d_out, int out_size, void* d_ws, size_t ws_size,
                              hipStream_t stream) {
    const float* z  = (const float*)d_in[0];
    const float* a0 = (const float*)d_in[1];
    const float* bk = (const float*)d_in[2];
    const float* ck = (const float*)d_in[3];
    const float* dk = (const float*)d_in[4];
    float* out = (float*)d_out;

    const int B      = in_sizes[0] / 16;       // z is [B,16]
    const int ntiles = B / 32;                 // 32 batch rows per wave-tile

    // 2 tiles/wave, 4 waves/block -> 8 tiles/block; 8192 blocks at B=2M
    const int blocks = (ntiles + 7) / 8;
    hipLaunchKernelGGL(mave_kernel, dim3(blocks), dim3(256), 0, stream,
                       z, a0, bk, ck, dk, out, ntiles);
}